// Round 3
// baseline (76.775 us; speedup 1.0000x reference)
//
#include <hip/hip_runtime.h>
#include <hip/hip_fp16.h>

// Problem: BS=64, K=4, PTS=5, RES=28, STEPS=500. All f32. Out (64,1,28,28).
//
// History: R5 flag-sync fusion regressed (cross-block sync). R6: t-stride 2
// (TSUB=250), 72.2us. R7 FAILED (+2.1): t-split kept per-CU LDS cycles const.
// R8 (4x4 reg tiling): dot LDS cycles 17.8k->4.8k cy/CU, predicted -5.4us,
// got -0.8 -> kernel cycles are NOT the dominant term. Total decomposes as
// ~39.3us harness poison fill (256MiB @85% HBM, fixed) + ~20us reset memsets
// + graph node gaps + ~10us our kernels.
//
// R9 change (structural): ONE kernel, grid=64 (block per image), 1024 thr =
// 4 strokes x 256 parallel (16 waves/CU, 4/SIMD). Ex/Ey stored fp16 as
// half2 t-pairs so 4 strokes fit LDS (120KB). Dot: 2 MACs per half2 pair
// (cvt+fma hides under LDS-bound reads). Per-stroke max+tanh and the K-sum
// + final tanh all in-block -> combine dispatch GONE, ws UNUSED.
// Same t-grid (steps 0,2,...,498) -> subsampling error unchanged; fp16
// storage adds <=5e-4 rel (RN; uniform bias cancels in maxnorm).
#define BSZ    64
#define KK     4
#define NPTS   5
#define RES    28
#define NSTEPS 500
#define TSUB   250              // sampled t-steps (stride 2 over 500)
#define TPAIR  125              // half2-packed t pairs
#define NPIX   (RES * RES)      // 784
#define EPSV   1e-6f

__global__ __launch_bounds__(1024) void fused_kernel(
    const float* __restrict__ z_pres,
    const float* __restrict__ z_what,
    const float* __restrict__ z_where,
    const float* __restrict__ sigma_p,
    const float* __restrict__ slope_strk_p,
    const float* __restrict__ slope_p,
    float* __restrict__ out)
{
    __shared__ float sC[KK][2][TSUB];                            // 8 KB
    __shared__ __align__(16) unsigned int sE[KK][2][TPAIR * RES]; // 112 KB
    __shared__ float sRed[16];

    const int b   = blockIdx.x;
    const int tid = threadIdx.x;
    const int q   = tid >> 8;       // stroke 0..3
    const int tq  = tid & 255;      // thread within stroke
    const int bk  = b * KK + q;

    const float s   = z_where[bk * 3 + 0];
    const float shx = z_where[bk * 3 + 1];
    const float shy = z_where[bk * 3 + 2];

    float px[NPTS], py[NPTS];
#pragma unroll
    for (int p = 0; p < NPTS; ++p) {
        px[p] = z_what[(bk * NPTS + p) * 2 + 0] * s + shx;
        py[p] = z_what[(bk * NPTS + p) * 2 + 1] * s + shy;
    }

    // Bernstein basis (deg 4) at t = (2j)/499, dotted with ctrl pts -> LDS.
    if (tq < TSUB) {
        int   j  = tq;
        float tt = (float)(2 * j) * (1.0f / (float)(NSTEPS - 1));
        float u  = 1.0f - tt;
        float u2 = u * u, t2 = tt * tt;
        float c0 = u2 * u2;
        float c1 = 4.0f * tt * u2 * u;
        float c2 = 6.0f * t2 * u2;
        float c3 = 4.0f * t2 * tt * u;
        float c4 = t2 * t2;
        sC[q][0][j] = c0*px[0] + c1*px[1] + c2*px[2] + c3*px[3] + c4*px[4];
        sC[q][1][j] = c0*py[0] + c1*py[1] + c2*py[2] + c3*py[3] + c4*py[4];
    }
    __syncthreads();

    const float sigma = sigma_p[0];
    const float inv   = 1.0f / (2.0f * sigma * sigma);

    // Fill Ex/Ey as half2 t-pairs: sE[q][0][tp*28+x] = (Ex[2tp][x],Ex[2tp+1][x]).
    // Group = (tp, 4-wide x block): 125*7 = 875 groups per stroke.
    for (int g = tq; g < TPAIR * 7; g += 256) {
        int tp = g / 7;
        int x0 = (g - tp * 7) * 4;
        float2 cx = *(const float2*)&sC[q][0][2 * tp];
        float2 cy = *(const float2*)&sC[q][1][2 * tp];
        unsigned ex[4], ey[4];
#pragma unroll
        for (int i = 0; i < 4; ++i) {
            float gg  = (float)(x0 + i) * (1.0f / (float)(RES - 1));
            float dx0 = gg - cx.x, dx1 = gg - cx.y;
            float dy0 = gg - cy.x, dy1 = gg - cy.y;
            __half2 hx = __floats2half2_rn(__expf(-dx0 * dx0 * inv),
                                           __expf(-dx1 * dx1 * inv));
            __half2 hy = __floats2half2_rn(__expf(-dy0 * dy0 * inv),
                                           __expf(-dy1 * dy1 * inv));
            ex[i] = *(unsigned*)&hx;
            ey[i] = *(unsigned*)&hy;
        }
        *(uint4*)&sE[q][0][tp * RES + x0] = make_uint4(ex[0], ex[1], ex[2], ex[3]);
        *(uint4*)&sE[q][1][tp * RES + x0] = make_uint4(ey[0], ey[1], ey[2], ey[3]);
    }
    __syncthreads();

    // 4x4 register-tiled outer-product dot over 125 t-pairs, 5 chunks of 25.
    const int  tile  = tq % 49;
    const int  chunk = tq / 49;
    const bool act   = (tq < 245);
    const int  ty    = (tile / 7) * 4;
    const int  tx    = (tile % 7) * 4;

    float a[4][4] = {{0.f}};
    if (act) {
        const unsigned* exb = &sE[q][0][tx];
        const unsigned* eyb = &sE[q][1][ty];
        const int tp1 = chunk * 25 + 25;
#pragma unroll 5
        for (int tp = chunk * 25; tp < tp1; ++tp) {
            uint4 xu = *(const uint4*)(exb + tp * RES);   // 4 half2 (x, t-pair)
            uint4 yu = *(const uint4*)(eyb + tp * RES);   // 4 half2 (y, t-pair)
            float2 xf[4], yf[4];
            xf[0] = __half22float2(*(__half2*)&xu.x);
            xf[1] = __half22float2(*(__half2*)&xu.y);
            xf[2] = __half22float2(*(__half2*)&xu.z);
            xf[3] = __half22float2(*(__half2*)&xu.w);
            yf[0] = __half22float2(*(__half2*)&yu.x);
            yf[1] = __half22float2(*(__half2*)&yu.y);
            yf[2] = __half22float2(*(__half2*)&yu.z);
            yf[3] = __half22float2(*(__half2*)&yu.w);
#pragma unroll
            for (int r = 0; r < 4; ++r)
#pragma unroll
                for (int c = 0; c < 4; ++c)
                    a[r][c] += yf[r].x * xf[c].x + yf[r].y * xf[c].y;
        }
    }
    __syncthreads();   // all dot reads of sE done -> safe to reuse as scratch

    // Partials into reused sE region: pacc[q][chunk][784] (15680 floats).
    float* pacc = (float*)&sE[0][0][0];
    if (act) {
        float* base = pacc + (q * 5 + chunk) * NPIX + ty * RES + tx;
#pragma unroll
        for (int r = 0; r < 4; ++r)
            *(float4*)(base + r * RES) = make_float4(a[r][0], a[r][1], a[r][2], a[r][3]);
    }
    __syncthreads();

    // Per-pixel sum over chunks; per stroke, threads 0..195 own 4 px of a row.
    const bool own = (tq < 196);
    const int  y   = tq / 7;
    const int  x0o = (tq % 7) * 4;
    float acc[4] = {0.f, 0.f, 0.f, 0.f};
    if (own) {
        const float* basep = pacc + q * 5 * NPIX + y * RES + x0o;
#pragma unroll
        for (int c = 0; c < 5; ++c) {
            float4 v = *(const float4*)(basep + c * NPIX);
            acc[0] += v.x; acc[1] += v.y; acc[2] += v.z; acc[3] += v.w;
        }
    }

    // Per-stroke max: wave shfl-reduce, then max of this stroke's 4 waves.
    float m = 0.f;
#pragma unroll
    for (int sl = 0; sl < 4; ++sl) m = fmaxf(m, acc[sl]);
    for (int off = 32; off > 0; off >>= 1)
        m = fmaxf(m, __shfl_down(m, off, 64));
    if ((tid & 63) == 0) sRed[tid >> 6] = m;
    __syncthreads();
    m = fmaxf(fmaxf(sRed[4 * q], sRed[4 * q + 1]),
              fmaxf(sRed[4 * q + 2], sRed[4 * q + 3]));

    const float zp    = z_pres[bk];               // uniform[0,1) -> >= 0
    const float denom = 1.0f / (m * zp + EPSV);   // max(acc*zp) == max(acc)*zp
    const float sstrk = slope_strk_p[0];
    const float itnh  = 1.0f / tanhf(sstrk);

    // Tanh-normed stroke -> simg[q][784] (disjoint from pacc words: offset 16384).
    float* simg = pacc + 16384;
    if (own) {
        float4 o;   // note y*28 + x0o == 4*tq for tq<196
        o.x = tanhf(acc[0] * zp * denom * sstrk) * itnh;
        o.y = tanhf(acc[1] * zp * denom * sstrk) * itnh;
        o.z = tanhf(acc[2] * zp * denom * sstrk) * itnh;
        o.w = tanhf(acc[3] * zp * denom * sstrk) * itnh;
        *(float4*)(simg + q * NPIX + tq * 4) = o;
    }
    __syncthreads();

    // Sum over K strokes + final tanh_norm(slope) -> out.
    if (tid < 196) {
        const float sl   = slope_p[0];
        const float itsl = 1.0f / tanhf(sl);
        float4 v0 = *(const float4*)(simg + 0 * NPIX + tid * 4);
        float4 v1 = *(const float4*)(simg + 1 * NPIX + tid * 4);
        float4 v2 = *(const float4*)(simg + 2 * NPIX + tid * 4);
        float4 v3 = *(const float4*)(simg + 3 * NPIX + tid * 4);
        float4 o;
        o.x = tanhf((v0.x + v1.x + v2.x + v3.x) * sl) * itsl;
        o.y = tanhf((v0.y + v1.y + v2.y + v3.y) * sl) * itsl;
        o.z = tanhf((v0.z + v1.z + v2.z + v3.z) * sl) * itsl;
        o.w = tanhf((v0.w + v1.w + v2.w + v3.w) * sl) * itsl;
        *(float4*)(out + b * NPIX + tid * 4) = o;
    }
}

extern "C" void kernel_launch(void* const* d_in, const int* in_sizes, int n_in,
                              void* d_out, int out_size, void* d_ws, size_t ws_size,
                              hipStream_t stream) {
    const float* z_pres     = (const float*)d_in[0];
    const float* z_what     = (const float*)d_in[1];
    const float* z_where    = (const float*)d_in[2];
    const float* sigma      = (const float*)d_in[3];
    const float* slope_strk = (const float*)d_in[4];
    const float* slope      = (const float*)d_in[5];
    (void)d_ws; (void)ws_size;   // workspace intentionally unused (R9 fusion)

    fused_kernel<<<BSZ, 1024, 0, stream>>>(z_pres, z_what, z_where,
                                           sigma, slope_strk, slope,
                                           (float*)d_out);
}

// Round 4
// 70.131 us; speedup vs baseline: 1.0947x; 1.0947x over previous
//
#include <hip/hip_runtime.h>

// Problem: BS=64, K=4, PTS=5, RES=28, STEPS=500. All f32. Out (64,1,28,28).
//
// History: R5 flag-sync fusion regressed. R6 t-stride2 (TSUB=250) 72.2us.
// R7 FAILED 74.3 (t-split: per-CU LDS cycles const). R8 4x4 reg-tiled dot
// 71.4us (best). R9 FAILED 76.8: single-kernel fusion packed 4 strokes on
// 64 CUs (112KB LDS, 1 block/CU) -> per-CU work x4 > saved dispatch.
//   -> per-CU cycles ARE visible in dur_us; 256-block spread is right.
//   -> poison fill (39.3us, 256MiB @85% HBM) runs even with ws unused:
//      unconditional harness floor (+ reset memsets + node gaps ~= 62-64us).
//
// R10: revert to R8 structure + micro-cuts, numerics untouched:
//  1. vectorized exp-fill: (t, 4x) groups, float4 LDS stores (4x fewer
//     write insts + addr calcs; same exp values).
//  2. fast tanh for args in [0,2.4]: (e^2x-1)/(e^2x+1) via __expf (~5 inst
//     vs ~25-inst libm tanhf), used 5x in strokes epilogue, 2x in combine.
//  3. combine: 4 px/thread, float4 IO, 49 blocks.
#define BSZ    64
#define KK     4
#define NPTS   5
#define RES    28
#define NSTEPS 500
#define TSUB   250              // sampled t-steps (stride 2 over 500)
#define TCH    50               // t-steps per chunk (5 chunks)
#define NPIX   (RES * RES)      // 784
#define EPSV   1e-6f

__device__ __forceinline__ float fast_tanh_pos(float x) {
    // valid for x >= 0 (all uses here); ~1e-6 rel error
    float e = __expf(2.0f * x);
    return __fdividef(e - 1.0f, e + 1.0f);
}

// One block per (b,k) stroke; 256 threads.
__global__ __launch_bounds__(256) void strokes_kernel(
    const float* __restrict__ z_pres,
    const float* __restrict__ z_what,
    const float* __restrict__ z_where,
    const float* __restrict__ sigma_p,
    const float* __restrict__ slope_strk_p,
    float* __restrict__ ws)
{
    __shared__ float sCx[TSUB];
    __shared__ float sCy[TSUB];
    __shared__ __align__(16) float sEx[TSUB * RES];   // Ex[t][x], row 112B
    __shared__ __align__(16) float sEy[TSUB * RES];   // Ey[t][y]
    __shared__ float sRed[4];

    const int bk  = blockIdx.x;   // b*K + k
    const int tid = threadIdx.x;

    const float s   = z_where[bk * 3 + 0];
    const float shx = z_where[bk * 3 + 1];
    const float shy = z_where[bk * 3 + 2];

    float px[NPTS], py[NPTS];
#pragma unroll
    for (int p = 0; p < NPTS; ++p) {
        px[p] = z_what[(bk * NPTS + p) * 2 + 0] * s + shx;
        py[p] = z_what[(bk * NPTS + p) * 2 + 1] * s + shy;
    }

    // Bernstein basis (deg 4) at t = (2j)/499, dotted with ctrl pts -> LDS.
    if (tid < TSUB) {
        int   j  = tid;
        float tt = (float)(2 * j) * (1.0f / (float)(NSTEPS - 1));
        float u  = 1.0f - tt;
        float u2 = u * u, t2 = tt * tt;
        float c0 = u2 * u2;
        float c1 = 4.0f * tt * u2 * u;
        float c2 = 6.0f * t2 * u2;
        float c3 = 4.0f * t2 * tt * u;
        float c4 = t2 * t2;
        sCx[j] = c0 * px[0] + c1 * px[1] + c2 * px[2] + c3 * px[3] + c4 * px[4];
        sCy[j] = c0 * py[0] + c1 * py[1] + c2 * py[2] + c3 * py[3] + c4 * py[4];
    }
    __syncthreads();

    const float sigma = sigma_p[0];
    const float inv   = 1.0f / (2.0f * sigma * sigma);

    // Fill Ex[t][x] = exp(-(g(x)-cx(t))^2 inv), Ey likewise.
    // Group = (t, 4-wide x block): 250*7 = 1750 groups, float4 stores.
    for (int g = tid; g < TSUB * 7; g += 256) {
        int t  = g / 7;
        int x0 = (g - t * 7) * 4;
        float cx = sCx[t];
        float cy = sCy[t];
        float4 ex, ey;
#pragma unroll
        for (int i = 0; i < 4; ++i) {
            float gg  = (float)(x0 + i) * (1.0f / (float)(RES - 1));
            float dxx = gg - cx;
            float dyy = gg - cy;
            (&ex.x)[i] = __expf(-dxx * dxx * inv);
            (&ey.x)[i] = __expf(-dyy * dyy * inv);
        }
        *(float4*)&sEx[t * RES + x0] = ex;   // 16B-aligned (112B rows)
        *(float4*)&sEy[t * RES + x0] = ey;
    }
    __syncthreads();

    // 4x4 register-tiled outer-product dot, t split in 5 chunks of 50.
    const int  tile  = tid % 49;
    const int  chunk = tid / 49;
    const bool act   = (tid < 245);
    const int  ty    = (tile / 7) * 4;
    const int  tx    = (tile % 7) * 4;

    float a[4][4] = {{0.f}};
    if (act) {
        const float* exb = sEx + tx;
        const float* eyb = sEy + ty;
        const int t1 = chunk * TCH + TCH;
#pragma unroll 2
        for (int t = chunk * TCH; t < t1; ++t) {
            float4 ex = *(const float4*)(exb + t * RES);  // 16B-aligned
            float4 ey = *(const float4*)(eyb + t * RES);  // 16B-aligned
#pragma unroll
            for (int r = 0; r < 4; ++r) {
                float yr = (&ey.x)[r];
                a[r][0] += yr * ex.x;
                a[r][1] += yr * ex.y;
                a[r][2] += yr * ex.z;
                a[r][3] += yr * ex.w;
            }
        }
    }
    __syncthreads();

    // Reduce the 5 t-chunks: partials into reused sEx region (3920 floats).
    float* pacc = sEx;
    if (act) {
        float* base = pacc + chunk * NPIX + ty * RES + tx;   // 16B-aligned
#pragma unroll
        for (int r = 0; r < 4; ++r)
            *(float4*)(base + r * RES) = make_float4(a[r][0], a[r][1], a[r][2], a[r][3]);
    }
    __syncthreads();

    // Per-pixel sum over chunks; threads 0..195 own 4 px of a row.
    const bool own = (tid < 196);
    const int  y   = tid / 7;
    const int  x0  = (tid % 7) * 4;
    float acc[4] = {0.f, 0.f, 0.f, 0.f};
    if (own) {
        const float* base = pacc + y * RES + x0;
#pragma unroll
        for (int c = 0; c < 5; ++c) {
            float4 v = *(const float4*)(base + c * NPIX);
            acc[0] += v.x; acc[1] += v.y; acc[2] += v.z; acc[3] += v.w;
        }
    }

    // Block max-reduction (inactive threads hold 0; all values >= 0).
    float m = 0.f;
#pragma unroll
    for (int sl = 0; sl < 4; ++sl) m = fmaxf(m, acc[sl]);
    for (int off = 32; off > 0; off >>= 1)
        m = fmaxf(m, __shfl_down(m, off, 64));
    if ((tid & 63) == 0) sRed[tid >> 6] = m;
    __syncthreads();
    m = fmaxf(fmaxf(sRed[0], sRed[1]), fmaxf(sRed[2], sRed[3]));

    const float zp    = z_pres[bk];               // uniform[0,1) -> >= 0
    const float denom = 1.0f / (m * zp + EPSV);   // max(acc*zp) == max(acc)*zp
    const float sstrk = slope_strk_p[0];
    const float itnh  = __fdividef(1.0f, fast_tanh_pos(sstrk));

    if (own) {
        float4 o;
        o.x = fast_tanh_pos(acc[0] * zp * denom * sstrk) * itnh;
        o.y = fast_tanh_pos(acc[1] * zp * denom * sstrk) * itnh;
        o.z = fast_tanh_pos(acc[2] * zp * denom * sstrk) * itnh;
        o.w = fast_tanh_pos(acc[3] * zp * denom * sstrk) * itnh;
        *(float4*)(ws + bk * NPIX + tid * 4) = o;
    }
}

// Sum over K strokes + final tanh_norm(slope); 4 px/thread, float4 IO.
__global__ __launch_bounds__(256) void combine_kernel(
    const float* __restrict__ ws,
    const float* __restrict__ slope_p,
    float* __restrict__ out)
{
    int idx = blockIdx.x * 256 + threadIdx.x;        // quad index
    if (idx >= BSZ * (NPIX / 4)) return;             // 64*196 = 12544
    int b  = idx / (NPIX / 4);
    int p4 = (idx - b * (NPIX / 4)) * 4;
    const float* base = ws + b * (KK * NPIX) + p4;
    float4 v0 = *(const float4*)(base + 0 * NPIX);
    float4 v1 = *(const float4*)(base + 1 * NPIX);
    float4 v2 = *(const float4*)(base + 2 * NPIX);
    float4 v3 = *(const float4*)(base + 3 * NPIX);
    const float sl   = slope_p[0];
    const float itsl = __fdividef(1.0f, fast_tanh_pos(sl));
    float4 o;
    o.x = fast_tanh_pos((v0.x + v1.x + v2.x + v3.x) * sl) * itsl;
    o.y = fast_tanh_pos((v0.y + v1.y + v2.y + v3.y) * sl) * itsl;
    o.z = fast_tanh_pos((v0.z + v1.z + v2.z + v3.z) * sl) * itsl;
    o.w = fast_tanh_pos((v0.w + v1.w + v2.w + v3.w) * sl) * itsl;
    *(float4*)(out + b * NPIX + p4) = o;
}

extern "C" void kernel_launch(void* const* d_in, const int* in_sizes, int n_in,
                              void* d_out, int out_size, void* d_ws, size_t ws_size,
                              hipStream_t stream) {
    const float* z_pres     = (const float*)d_in[0];
    const float* z_what     = (const float*)d_in[1];
    const float* z_where    = (const float*)d_in[2];
    const float* sigma      = (const float*)d_in[3];
    const float* slope_strk = (const float*)d_in[4];
    const float* slope      = (const float*)d_in[5];

    float* ws  = (float*)d_ws;          // 256*784 f32 = 784 KB scratch
    float* out = (float*)d_out;

    strokes_kernel<<<BSZ * KK, 256, 0, stream>>>(z_pres, z_what, z_where,
                                                 sigma, slope_strk, ws);
    combine_kernel<<<(BSZ * (NPIX / 4) + 255) / 256, 256, 0, stream>>>(ws, slope, out);
}

// Round 5
// 68.396 us; speedup vs baseline: 1.1225x; 1.0254x over previous
//
#include <hip/hip_runtime.h>

// Problem: BS=64, K=4, PTS=5, RES=28, STEPS=500. All f32. Out (64,1,28,28).
//
// History: R5 flag-sync fusion regressed. R6 t-stride2 (TSUB=250) 72.2us.
// R7 FAILED 74.3 (t-split: per-CU LDS cycles const). R8 4x4 reg-tiled dot
// 71.4. R9 FAILED 76.8 (single-kernel fusion: 4x per-CU work > 1 dispatch).
// R10 69.9-70.1 (vector exp-fill, fast tanh, float4 combine) — best.
// Decomposition: ~39.5us unconditional 256MiB poison fill (@85% HBM) +
// ~24us harness reset/memset/node-gap overhead + ~6us ours.
//
// R11: composite t-quadrature. Uniform stride-4 is UNSAFE: h~1.5sigma makes
// the one-sided sum at curve endpoints phase-dependent (+/-33% worst case).
// Safe: stride-2 near both t-ends (6 samples each — identical endpoint
// fidelity to the passing stride-2 grid), stride-4 interior with weight 2
// folded into Ex (exact nearest-neighbor binning of the 500-step sum;
// global x2 cancels in maxnorm). Interior aliasing at worst speed 5.6:
// 2exp(-2pi^2 sigma^2/h^2) ~ 3e-4. TS 250->131: exp + dot work x0.52.
//   samples: j<6 -> step 2j (0..10, w1) | 6<=j<125 -> 14+4(j-6) (14..486,
//   w2) | j>=125 -> 488+2(j-125) (488..498, w1). Coverage 12+476+12=500.
#define BSZ    64
#define KK     4
#define NPTS   5
#define RES    28
#define NSTEPS 500
#define TS     131              // composite t-samples
#define TCH    27               // chunk size (5 chunks; last = 23)
#define NPIX   (RES * RES)      // 784
#define EPSV   1e-6f

__device__ __forceinline__ float fast_tanh_pos(float x) {
    // valid for x >= 0 (all uses here); ~1e-6 rel error
    float e = __expf(2.0f * x);
    return __fdividef(e - 1.0f, e + 1.0f);
}

__device__ __forceinline__ int t_step(int j) {
    return (j < 6) ? 2 * j : (j < 125) ? 14 + 4 * (j - 6) : 488 + 2 * (j - 125);
}

// One block per (b,k) stroke; 256 threads.
__global__ __launch_bounds__(256) void strokes_kernel(
    const float* __restrict__ z_pres,
    const float* __restrict__ z_what,
    const float* __restrict__ z_where,
    const float* __restrict__ sigma_p,
    const float* __restrict__ slope_strk_p,
    float* __restrict__ ws)
{
    __shared__ float sCx[TS];
    __shared__ float sCy[TS];
    // Ex then Ey contiguous; TS*RES=3668 floats each (14672B, 16B-multiple).
    // Post-dot the first 5*784=3920 floats are reused as partial accumulators.
    __shared__ __align__(16) float sE[2 * TS * RES];
    __shared__ float sRed[4];
    float* const sEx = sE;
    float* const sEy = sE + TS * RES;

    const int bk  = blockIdx.x;   // b*K + k
    const int tid = threadIdx.x;

    const float s   = z_where[bk * 3 + 0];
    const float shx = z_where[bk * 3 + 1];
    const float shy = z_where[bk * 3 + 2];

    float px[NPTS], py[NPTS];
#pragma unroll
    for (int p = 0; p < NPTS; ++p) {
        px[p] = z_what[(bk * NPTS + p) * 2 + 0] * s + shx;
        py[p] = z_what[(bk * NPTS + p) * 2 + 1] * s + shy;
    }

    // Bernstein basis (deg 4) at t = t_step(j)/499, dotted with ctrl pts.
    if (tid < TS) {
        float tt = (float)t_step(tid) * (1.0f / (float)(NSTEPS - 1));
        float u  = 1.0f - tt;
        float u2 = u * u, t2 = tt * tt;
        float c0 = u2 * u2;
        float c1 = 4.0f * tt * u2 * u;
        float c2 = 6.0f * t2 * u2;
        float c3 = 4.0f * t2 * tt * u;
        float c4 = t2 * t2;
        sCx[tid] = c0 * px[0] + c1 * px[1] + c2 * px[2] + c3 * px[3] + c4 * px[4];
        sCy[tid] = c0 * py[0] + c1 * py[1] + c2 * py[2] + c3 * py[3] + c4 * py[4];
    }
    __syncthreads();

    const float sigma = sigma_p[0];
    const float inv   = 1.0f / (2.0f * sigma * sigma);

    // Fill Ex[j][x] = w_j * exp(-(g(x)-cx_j)^2 inv), Ey[j][y] = exp(...).
    // Group = (j, 4-wide x block): 131*7 = 917 groups, float4 stores.
    for (int g = tid; g < TS * 7; g += 256) {
        int j  = g / 7;
        int x0 = (g - j * 7) * 4;
        float cx = sCx[j];
        float cy = sCy[j];
        float w  = (j >= 6 && j < 125) ? 2.0f : 1.0f;   // quadrature weight
        float4 ex, ey;
#pragma unroll
        for (int i = 0; i < 4; ++i) {
            float gg  = (float)(x0 + i) * (1.0f / (float)(RES - 1));
            float dxx = gg - cx;
            float dyy = gg - cy;
            (&ex.x)[i] = w * __expf(-dxx * dxx * inv);
            (&ey.x)[i] = __expf(-dyy * dyy * inv);
        }
        *(float4*)&sEx[j * RES + x0] = ex;   // 16B-aligned (112B rows)
        *(float4*)&sEy[j * RES + x0] = ey;
    }
    __syncthreads();

    // 4x4 register-tiled outer-product dot, j split in 5 chunks of <=27.
    const int  tile  = tid % 49;
    const int  chunk = tid / 49;
    const bool act   = (tid < 245);
    const int  ty    = (tile / 7) * 4;
    const int  tx    = (tile % 7) * 4;

    float a[4][4] = {{0.f}};
    if (act) {
        const float* exb = sEx + tx;
        const float* eyb = sEy + ty;
        const int j1 = min(chunk * TCH + TCH, TS);
        for (int j = chunk * TCH; j < j1; ++j) {
            float4 ex = *(const float4*)(exb + j * RES);  // 16B-aligned
            float4 ey = *(const float4*)(eyb + j * RES);  // 16B-aligned
#pragma unroll
            for (int r = 0; r < 4; ++r) {
                float yr = (&ey.x)[r];
                a[r][0] += yr * ex.x;
                a[r][1] += yr * ex.y;
                a[r][2] += yr * ex.z;
                a[r][3] += yr * ex.w;
            }
        }
    }
    __syncthreads();

    // Reduce the 5 chunks: partials into reused sE region (3920 floats).
    float* pacc = sE;
    if (act) {
        float* base = pacc + chunk * NPIX + ty * RES + tx;   // 16B-aligned
#pragma unroll
        for (int r = 0; r < 4; ++r)
            *(float4*)(base + r * RES) = make_float4(a[r][0], a[r][1], a[r][2], a[r][3]);
    }
    __syncthreads();

    // Per-pixel sum over chunks; threads 0..195 own 4 px of a row.
    const bool own = (tid < 196);
    const int  y   = tid / 7;
    const int  x0  = (tid % 7) * 4;
    float acc[4] = {0.f, 0.f, 0.f, 0.f};
    if (own) {
        const float* base = pacc + y * RES + x0;
#pragma unroll
        for (int c = 0; c < 5; ++c) {
            float4 v = *(const float4*)(base + c * NPIX);
            acc[0] += v.x; acc[1] += v.y; acc[2] += v.z; acc[3] += v.w;
        }
    }

    // Block max-reduction (inactive threads hold 0; all values >= 0).
    float m = 0.f;
#pragma unroll
    for (int sl = 0; sl < 4; ++sl) m = fmaxf(m, acc[sl]);
    for (int off = 32; off > 0; off >>= 1)
        m = fmaxf(m, __shfl_down(m, off, 64));
    if ((tid & 63) == 0) sRed[tid >> 6] = m;
    __syncthreads();
    m = fmaxf(fmaxf(sRed[0], sRed[1]), fmaxf(sRed[2], sRed[3]));

    const float zp    = z_pres[bk];               // uniform[0,1) -> >= 0
    const float denom = 1.0f / (m * zp + EPSV);   // max(acc*zp) == max(acc)*zp
    const float sstrk = slope_strk_p[0];
    const float itnh  = __fdividef(1.0f, fast_tanh_pos(sstrk));

    if (own) {
        float4 o;
        o.x = fast_tanh_pos(acc[0] * zp * denom * sstrk) * itnh;
        o.y = fast_tanh_pos(acc[1] * zp * denom * sstrk) * itnh;
        o.z = fast_tanh_pos(acc[2] * zp * denom * sstrk) * itnh;
        o.w = fast_tanh_pos(acc[3] * zp * denom * sstrk) * itnh;
        *(float4*)(ws + bk * NPIX + tid * 4) = o;
    }
}

// Sum over K strokes + final tanh_norm(slope); 4 px/thread, float4 IO.
__global__ __launch_bounds__(256) void combine_kernel(
    const float* __restrict__ ws,
    const float* __restrict__ slope_p,
    float* __restrict__ out)
{
    int idx = blockIdx.x * 256 + threadIdx.x;        // quad index
    if (idx >= BSZ * (NPIX / 4)) return;             // 64*196 = 12544
    int b  = idx / (NPIX / 4);
    int p4 = (idx - b * (NPIX / 4)) * 4;
    const float* base = ws + b * (KK * NPIX) + p4;
    float4 v0 = *(const float4*)(base + 0 * NPIX);
    float4 v1 = *(const float4*)(base + 1 * NPIX);
    float4 v2 = *(const float4*)(base + 2 * NPIX);
    float4 v3 = *(const float4*)(base + 3 * NPIX);
    const float sl   = slope_p[0];
    const float itsl = __fdividef(1.0f, fast_tanh_pos(sl));
    float4 o;
    o.x = fast_tanh_pos((v0.x + v1.x + v2.x + v3.x) * sl) * itsl;
    o.y = fast_tanh_pos((v0.y + v1.y + v2.y + v3.y) * sl) * itsl;
    o.z = fast_tanh_pos((v0.z + v1.z + v2.z + v3.z) * sl) * itsl;
    o.w = fast_tanh_pos((v0.w + v1.w + v2.w + v3.w) * sl) * itsl;
    *(float4*)(out + b * NPIX + p4) = o;
}

extern "C" void kernel_launch(void* const* d_in, const int* in_sizes, int n_in,
                              void* d_out, int out_size, void* d_ws, size_t ws_size,
                              hipStream_t stream) {
    const float* z_pres     = (const float*)d_in[0];
    const float* z_what     = (const float*)d_in[1];
    const float* z_where    = (const float*)d_in[2];
    const float* sigma      = (const float*)d_in[3];
    const float* slope_strk = (const float*)d_in[4];
    const float* slope      = (const float*)d_in[5];

    float* ws  = (float*)d_ws;          // 256*784 f32 = 784 KB scratch
    float* out = (float*)d_out;

    strokes_kernel<<<BSZ * KK, 256, 0, stream>>>(z_pres, z_what, z_where,
                                                 sigma, slope_strk, ws);
    combine_kernel<<<(BSZ * (NPIX / 4) + 255) / 256, 256, 0, stream>>>(ws, slope, out);
}